// Round 7
// baseline (104.714 us; speedup 1.0000x reference)
//
#include <hip/hip_runtime.h>

// DeepQNetwork fused forward:  x(B,15) -> onehot(36) -> 128 -> 512 -> 40
// Transposed MFMA scheme (features = M, batch rows = N), v_mfma_f32_16x16x32_bf16:
//   A frag (weights, prepacked fragment-linear in ws): lane = A[m=l16][k=quad*8+j]
//   B frag (activations): lane = act[row=l16][feat=quad*8+j] -> ds_read_b128
//   C/D: lane reg r = D[feat=quad*4+r][row=l16] -> pack 4 feats -> one ds_write_b64
// R7 (occupancy x shared-stream): 32 rows/wave -> 4096 waves -> 16 waves/CU
// (4/SIMD, was 2/SIMD -- the R4-R6 invariant wall), with W2 still LDS-shared
// (R5 structure) so the R3 private-stream thrash cannot recur. 4-wave blocks,
// grid 1024 = exactly 4 blocks/CU; VGPR halves (~120) -> launch_bounds(256,4).
// W4 register-hoisted per chunk (R6). LDS 34816B/block.

typedef short bf16x8 __attribute__((ext_vector_type(8)));
typedef float f32x4 __attribute__((ext_vector_type(4)));
typedef unsigned int u32;

#define NW1F 8192              // 16 frags  (8 mt * 2 ks)
#define NW2F 65536             // 128 frags (32 mt * 4 ks)
#define NW4F 24576             // 48 frags  (3 mt * 16 ks)
#define PACK_TOTAL (NW1F + NW2F + NW4F)   // 98304 shorts = 192 KB of ws
#define PACK_THREADS (PACK_TOTAL / 8)     // one b128 store per thread

__device__ __forceinline__ unsigned short f2bf(float f) {
  union { float f; unsigned u; } a; a.f = f;
  unsigned r = a.u + 0x7fffu + ((a.u >> 16) & 1u);
  return (unsigned short)(r >> 16);
}
// gfx950 packed convert, RNE: two f32 -> bf16x2 in one VALU op.
__device__ __forceinline__ u32 cvtpk(float lo, float hi) {
  u32 r;
  asm("v_cvt_pk_bf16_f32 %0, %1, %2" : "=v"(r) : "v"(lo), "v"(hi));
  return r;
}
// async global->LDS, 16B per lane: lds[base + lane*16] <- g[lane*16]; 1KB/wave-call.
__device__ __forceinline__ void glds16(const void* g, void* l) {
  __builtin_amdgcn_global_load_lds(
      (const __attribute__((address_space(1))) void*)g,
      (__attribute__((address_space(3))) void*)l, 16, 0, 0);
}

// Prepack W1^T (128x64, K-pad 36->64), W2^T (512x128), W4^T (48x512, M-pad 40->48)
// as A-fragment-linear bf16: frag*512 + lane*8 + j = A[m=mt*16+l16][k=ks*32+quad*8+j].
__global__ void pack_weights(const float* __restrict__ W1,
                             const float* __restrict__ W2,
                             const float* __restrict__ W4,
                             unsigned short* __restrict__ wf) {
  int t = blockIdx.x * 256 + threadIdx.x;
  if (t >= PACK_THREADS) return;
  int fid = t >> 6, lane = t & 63;
  int l16 = lane & 15, quad = lane >> 4;
  float vals[8];
  if (fid < 16) {                       // W1: fid = mt*2+ks
    int mt = fid >> 1, ks = fid & 1;
    int m = mt * 16 + l16, k0 = ks * 32 + quad * 8;
#pragma unroll
    for (int j = 0; j < 8; ++j) { int k = k0 + j; vals[j] = (k < 36) ? W1[k * 128 + m] : 0.f; }
  } else if (fid < 144) {               // W2: fid-16 = mt*4+ks
    int f = fid - 16, mt = f >> 2, ks = f & 3;
    int m = mt * 16 + l16, k0 = ks * 32 + quad * 8;
#pragma unroll
    for (int j = 0; j < 8; ++j) vals[j] = W2[(k0 + j) * 512 + m];
  } else {                              // W4: fid-144 = mt*16+ks
    int f = fid - 144, mt = f >> 4, ks = f & 15;
    int m = mt * 16 + l16, k0 = ks * 32 + quad * 8;
#pragma unroll
    for (int j = 0; j < 8; ++j) vals[j] = (m < 40) ? W4[(k0 + j) * 40 + m] : 0.f;
  }
  u32 p[4];
#pragma unroll
  for (int j = 0; j < 4; ++j) p[j] = cvtpk(vals[2 * j], vals[2 * j + 1]);
  *(bf16x8*)(wf + (size_t)t * 8) = *(bf16x8*)p;
}

// 256 threads = 4 waves; each wave privately owns 32 rows (2 N-groups of 16).
// Activation LDS traffic is wave-private (DS in-order per wave); barriers exist
// only for the shared W2 staging pipeline.
__global__ __launch_bounds__(256, 4) void dqn_fused(
    const float* __restrict__ x,
    const unsigned short* __restrict__ wf,
    const float* __restrict__ b1,
    const float* __restrict__ b2,
    const float* __restrict__ b4,
    float* __restrict__ out) {
  __shared__ __align__(16) unsigned short sBuf[4 * 32 * 72];  // 18432 B activations
  __shared__ __align__(16) unsigned short sW2[2 * 4096];      // 16384 B W2 dbuf
  // total 34816 B -> 4 blocks/CU (grid dispatches exactly 4/CU)

  const int tid  = threadIdx.x;
  const int lane = tid & 63;
  const int wave = tid >> 6;
  const int quad = lane >> 4;
  const int l16  = lane & 15;
  const int row0 = blockIdx.x << 7;              // 128 rows per block
  const int lr0  = wave * 32;
  unsigned short* su = sBuf + wave * (32 * 72);  // wave-private

  const unsigned short* w2f = wf + NW1F;
  const unsigned short* w4f = wf + NW1F + NW2F;

  // prologue: stage pipeline window 0 (frags 0..7 of W2 = 8KB; 2KB slice/wave).
  {
    const char* g = (const char*)w2f + wave * 2048 + lane * 16;
    char* l = (char*)sW2 + wave * 2048;
    glds16(g, l);
    glds16(g + 1024, l + 1024);
  }

  // ---- stage 1: one-hot input rows in LDS (bf16), K padded 36->64; 1 row/lane ----
  if (lane < 32) {
    const float* xr = x + (size_t)(row0 + lr0 + lane) * 15;
    unsigned short* dst = su + lane * 72;
    bf16x8 z = {0, 0, 0, 0, 0, 0, 0, 0};
#pragma unroll
    for (int c = 8; c < 64; c += 8) *(bf16x8*)(dst + c) = z;   // zero cols 8..63
    u32 p[4];
#pragma unroll
    for (int i = 0; i < 4; ++i) p[i] = cvtpk(xr[2 * i], xr[2 * i + 1]);
    *(bf16x8*)dst = *(bf16x8*)p;                 // keep cols 0..7
    *(u32*)(dst + 8) = cvtpk(xr[8], xr[9]);      // keep cols 8..9
    dst[10] = f2bf(xr[10]);                      // keep col 10
    int hold = (int)xr[11]; hold = hold < 0 ? 0 : (hold > 3 ? 3 : hold);
    dst[11 + hold] = 0x3F80;                     // bf16 1.0
#pragma unroll
    for (int t = 0; t < 3; ++t) {
      int nx = (int)xr[12 + t] - 1; nx = nx < 0 ? 0 : (nx > 6 ? 6 : nx);
      dst[15 + t * 7 + nx] = 0x3F80;
    }
  }

  const f32x4 vzero = {0.f, 0.f, 0.f, 0.f};

  // ---- stage 2: h1^T = relu(W1^T @ inp^T + b1), two mt-halves; af1 frags to regs.
  bf16x8 ib[2][2];
#pragma unroll
  for (int rg = 0; rg < 2; ++rg)
#pragma unroll
    for (int ks = 0; ks < 2; ++ks)
      ib[rg][ks] = *(const bf16x8*)(su + (rg * 16 + l16) * 72 + ks * 32 + quad * 8);

  bf16x8 af1[2][4];   // [rg][ks_out]: h1 B-frags, filled per half
#pragma unroll
  for (int half = 0; half < 2; ++half) {
    f32x4 acc1[4][2];   // [mtl][rg]
#pragma unroll
    for (int mtl = 0; mtl < 4; ++mtl)
#pragma unroll
      for (int rg = 0; rg < 2; ++rg) acc1[mtl][rg] = vzero;

#pragma unroll
    for (int mtl = 0; mtl < 4; ++mtl)
#pragma unroll
      for (int ks = 0; ks < 2; ++ks) {
        int mt = half * 4 + mtl;
        bf16x8 wa = *(const bf16x8*)(wf + (size_t)((mt * 2 + ks) * 64 + lane) * 8);
#pragma unroll
        for (int rg = 0; rg < 2; ++rg)
          acc1[mtl][rg] = __builtin_amdgcn_mfma_f32_16x16x32_bf16(wa, ib[rg][ks], acc1[mtl][rg], 0, 0, 0);
      }
#pragma unroll
    for (int mtl = 0; mtl < 4; ++mtl) {
      f32x4 bias = *(const f32x4*)(b1 + (half * 4 + mtl) * 16 + quad * 4);
#pragma unroll
      for (int rg = 0; rg < 2; ++rg) {
        float v0 = fmaxf(acc1[mtl][rg][0] + bias[0], 0.f);
        float v1 = fmaxf(acc1[mtl][rg][1] + bias[1], 0.f);
        float v2 = fmaxf(acc1[mtl][rg][2] + bias[2], 0.f);
        float v3 = fmaxf(acc1[mtl][rg][3] + bias[3], 0.f);
        uint2 pk = {cvtpk(v0, v1), cvtpk(v2, v3)};
        *(uint2*)(su + (rg * 16 + l16) * 72 + mtl * 16 + quad * 4) = pk;
      }
    }
#pragma unroll
    for (int rg = 0; rg < 2; ++rg)
#pragma unroll
      for (int ksl = 0; ksl < 2; ++ksl)
        af1[rg][half * 2 + ksl] =
            *(const bf16x8*)(su + (rg * 16 + l16) * 72 + ksl * 32 + quad * 8);
  }

  f32x4 accO[3][2];
#pragma unroll
  for (int mt = 0; mt < 3; ++mt)
#pragma unroll
    for (int rg = 0; rg < 2; ++rg) accO[mt][rg] = vzero;

  // ---- stage 3: 16-window W2 pipeline (8 chunks x 2 halves); L3 after each chunk ----
  for (int chunk = 0; chunk < 8; ++chunk) {
    bf16x8 w4r[2][3];   // W4 frags for this chunk, register-prefetched
#pragma unroll
    for (int half = 0; half < 2; ++half) {
      const int s = chunk * 2 + half;
      // Arrival of window s (issuers drained vmcnt before barrier) + all waves
      // done reading window s-1's buffer -> safe to overwrite.
      __syncthreads();
      if (s < 15) {   // prefetch window s+1 into the other buffer (2KB/wave slice)
        const char* g = (const char*)w2f + (size_t)(s + 1) * 8192 + wave * 2048 + lane * 16;
        char* l = (char*)sW2 + ((s + 1) & 1) * 8192 + wave * 2048;
        glds16(g, l);
        glds16(g + 1024, l + 1024);
      }
      if (half == 0) {
        // hoist W4 loads for this chunk: latency overlaps both W2 windows
#pragma unroll
        for (int ks3 = 0; ks3 < 2; ++ks3)
#pragma unroll
          for (int mt3 = 0; mt3 < 3; ++mt3)
            w4r[ks3][mt3] = *(const bf16x8*)(
                w4f + (size_t)((mt3 * 16 + chunk * 2 + ks3) * 64 + lane) * 8);
      }
      const unsigned short* wbuf = sW2 + (s & 1) * 4096;

      f32x4 acc2[2][2];   // [ml][rg], ml = mtl - half*2
#pragma unroll
      for (int ml = 0; ml < 2; ++ml)
#pragma unroll
        for (int rg = 0; rg < 2; ++rg) acc2[ml][rg] = vzero;

#pragma unroll
      for (int ks = 0; ks < 4; ++ks)
#pragma unroll
        for (int ml = 0; ml < 2; ++ml) {
          bf16x8 w = *(const bf16x8*)(wbuf + (ml * 4 + ks) * 512 + lane * 8);
#pragma unroll
          for (int rg = 0; rg < 2; ++rg)
            acc2[ml][rg] = __builtin_amdgcn_mfma_f32_16x16x32_bf16(w, af1[rg][ks], acc2[ml][rg], 0, 0, 0);
        }
      // bias+relu -> h2 cols (half*2+ml)*16 + quad*4, wave-private b64 writes
#pragma unroll
      for (int ml = 0; ml < 2; ++ml) {
        int mtl = half * 2 + ml;
        f32x4 bias = *(const f32x4*)(b2 + chunk * 64 + mtl * 16 + quad * 4);
#pragma unroll
        for (int rg = 0; rg < 2; ++rg) {
          float v0 = fmaxf(acc2[ml][rg][0] + bias[0], 0.f);
          float v1 = fmaxf(acc2[ml][rg][1] + bias[1], 0.f);
          float v2 = fmaxf(acc2[ml][rg][2] + bias[2], 0.f);
          float v3 = fmaxf(acc2[ml][rg][3] + bias[3], 0.f);
          uint2 pk = {cvtpk(v0, v1), cvtpk(v2, v3)};
          *(uint2*)(su + (rg * 16 + l16) * 72 + mtl * 16 + quad * 4) = pk;
        }
      }
    }
    // L3 partial on this chunk's 64 feats (h2 wave-private; W4 from registers)
#pragma unroll
    for (int ks3 = 0; ks3 < 2; ++ks3) {
      bf16x8 h[2];
#pragma unroll
      for (int rg = 0; rg < 2; ++rg)
        h[rg] = *(const bf16x8*)(su + (rg * 16 + l16) * 72 + ks3 * 32 + quad * 8);
#pragma unroll
      for (int mt3 = 0; mt3 < 3; ++mt3)
#pragma unroll
        for (int rg = 0; rg < 2; ++rg)
          accO[mt3][rg] = __builtin_amdgcn_mfma_f32_16x16x32_bf16(w4r[ks3][mt3], h[rg], accO[mt3][rg], 0, 0, 0);
    }
  }

  // ---- epilogue: +b4, float4 stores (lane holds 4 consecutive out-cols) ----
#pragma unroll
  for (int mt3 = 0; mt3 < 3; ++mt3) {
    int colbase = mt3 * 16 + quad * 4;
    if (colbase < 40) {                      // drops pad cols 40..47
      f32x4 bias = *(const f32x4*)(b4 + colbase);
#pragma unroll
      for (int rg = 0; rg < 2; ++rg) {
        f32x4 v = accO[mt3][rg] + bias;
        size_t row = (size_t)(row0 + lr0 + rg * 16 + l16);
        *(f32x4*)(out + row * 40 + colbase) = v;
      }
    }
  }
}

extern "C" void kernel_launch(void* const* d_in, const int* in_sizes, int n_in,
                              void* d_out, int out_size, void* d_ws, size_t ws_size,
                              hipStream_t stream) {
  const float* x  = (const float*)d_in[0];
  const float* W1 = (const float*)d_in[1];
  const float* b1 = (const float*)d_in[2];
  const float* W2 = (const float*)d_in[3];
  const float* b2 = (const float*)d_in[4];
  const float* W4 = (const float*)d_in[5];
  const float* b4 = (const float*)d_in[6];
  float* out = (float*)d_out;
  unsigned short* wf = (unsigned short*)d_ws;   // 192 KB of ws

  int B = in_sizes[0] / 15;

  hipLaunchKernelGGL(pack_weights, dim3((PACK_THREADS + 255) / 256), dim3(256), 0, stream,
                     W1, W2, W4, wf);
  hipLaunchKernelGGL(dqn_fused, dim3(B / 128), dim3(256), 0, stream,
                     x, wf, b1, b2, b4, out);
}

// Round 8
// 99.531 us; speedup vs baseline: 1.0521x; 1.0521x over previous
//
#include <hip/hip_runtime.h>

// DeepQNetwork fused forward:  x(B,15) -> onehot(36) -> 128 -> 512 -> 40
// Transposed MFMA scheme (features = M, batch rows = N), v_mfma_f32_16x16x32_bf16:
//   A frag (weights, prepacked fragment-linear in ws): lane = A[m=l16][k=quad*8+j]
//   B frag (activations): lane = act[row=l16][feat=quad*8+j] -> ds_read_b128
//   C/D: lane reg r = D[feat=quad*4+r][row=l16] -> pack 4 feats -> one ds_write_b64
// R8: ZERO barriers, ZERO W2 LDS. R4-R7 showed the barrier-pipelined W2 staging
// phase-locks all waves into the same pipe phase -> elapsed ~= SUM of pipe busy
// (MFMA+DS+VALU ~= 31us, matches R6's 34) instead of MAX (~12.4us MFMA floor).
// Fix = hipBLASLt-style register software pipeline: W2 frag-quads double-buffered
// in VGPRs via plain global loads issued one mtl-step (16 MFMAs ~= 310 cyc) ahead;
// no waitcnt-before-barrier drains; 8 free-drifting waves/CU co-schedule
// MFMA/DS/VMEM/VALU pipes. DS pipe now carries activations only.
// 2-wave blocks (64 rows/wave), grid 1024, LDS 18432B -> 4 blocks/CU.

typedef short bf16x8 __attribute__((ext_vector_type(8)));
typedef float f32x4 __attribute__((ext_vector_type(4)));
typedef unsigned int u32;

#define NW1F 8192              // 16 frags  (8 mt * 2 ks)
#define NW2F 65536             // 128 frags (32 mt * 4 ks)
#define NW4F 24576             // 48 frags  (3 mt * 16 ks)
#define PACK_TOTAL (NW1F + NW2F + NW4F)   // 98304 shorts = 192 KB of ws
#define PACK_THREADS (PACK_TOTAL / 8)     // one b128 store per thread

__device__ __forceinline__ unsigned short f2bf(float f) {
  union { float f; unsigned u; } a; a.f = f;
  unsigned r = a.u + 0x7fffu + ((a.u >> 16) & 1u);
  return (unsigned short)(r >> 16);
}
// gfx950 packed convert, RNE: two f32 -> bf16x2 in one VALU op.
__device__ __forceinline__ u32 cvtpk(float lo, float hi) {
  u32 r;
  asm("v_cvt_pk_bf16_f32 %0, %1, %2" : "=v"(r) : "v"(lo), "v"(hi));
  return r;
}

// Prepack W1^T (128x64, K-pad 36->64), W2^T (512x128), W4^T (48x512, M-pad 40->48)
// as A-fragment-linear bf16: frag*512 + lane*8 + j = A[m=mt*16+l16][k=ks*32+quad*8+j].
__global__ void pack_weights(const float* __restrict__ W1,
                             const float* __restrict__ W2,
                             const float* __restrict__ W4,
                             unsigned short* __restrict__ wf) {
  int t = blockIdx.x * 256 + threadIdx.x;
  if (t >= PACK_THREADS) return;
  int fid = t >> 6, lane = t & 63;
  int l16 = lane & 15, quad = lane >> 4;
  float vals[8];
  if (fid < 16) {                       // W1: fid = mt*2+ks
    int mt = fid >> 1, ks = fid & 1;
    int m = mt * 16 + l16, k0 = ks * 32 + quad * 8;
#pragma unroll
    for (int j = 0; j < 8; ++j) { int k = k0 + j; vals[j] = (k < 36) ? W1[k * 128 + m] : 0.f; }
  } else if (fid < 144) {               // W2: fid-16 = mt*4+ks
    int f = fid - 16, mt = f >> 2, ks = f & 3;
    int m = mt * 16 + l16, k0 = ks * 32 + quad * 8;
#pragma unroll
    for (int j = 0; j < 8; ++j) vals[j] = W2[(k0 + j) * 512 + m];
  } else {                              // W4: fid-144 = mt*16+ks
    int f = fid - 144, mt = f >> 4, ks = f & 15;
    int m = mt * 16 + l16, k0 = ks * 32 + quad * 8;
#pragma unroll
    for (int j = 0; j < 8; ++j) vals[j] = (m < 40) ? W4[(k0 + j) * 40 + m] : 0.f;
  }
  u32 p[4];
#pragma unroll
  for (int j = 0; j < 4; ++j) p[j] = cvtpk(vals[2 * j], vals[2 * j + 1]);
  *(bf16x8*)(wf + (size_t)t * 8) = *(bf16x8*)p;
}

// 128 threads = 2 waves; each wave privately owns 64 rows (4 N-groups of 16).
// All LDS traffic is wave-private (DS ops complete in order per wave) -> the
// kernel contains NO __syncthreads / s_barrier at all.
__global__ __launch_bounds__(128, 2) void dqn_fused(
    const float* __restrict__ x,
    const unsigned short* __restrict__ wf,
    const float* __restrict__ b1,
    const float* __restrict__ b2,
    const float* __restrict__ b4,
    float* __restrict__ out) {
  __shared__ __align__(16) unsigned short sBuf[2 * 64 * 72];  // 18432 B -> 4 blocks/CU

  const int tid  = threadIdx.x;
  const int lane = tid & 63;
  const int wave = tid >> 6;                     // 0 or 1
  const int quad = lane >> 4;
  const int l16  = lane & 15;
  const int row0 = blockIdx.x << 7;              // 128 rows per block
  const int lr0  = wave * 64;
  unsigned short* su = sBuf + wave * (64 * 72);  // wave-private

  const unsigned short* w2f = wf + NW1F;
  const unsigned short* w4f = wf + NW1F + NW2F;
  const unsigned short* w2p = w2f + lane * 8;    // frag f lives at w2p + f*512

  // software-pipeline prologue: W2 frag-quad 0 (chunk0, mtl0) into registers now;
  // its latency overlaps input staging + the whole L1 GEMM.
  bf16x8 curW[4];
#pragma unroll
  for (int k = 0; k < 4; ++k) curW[k] = *(const bf16x8*)(w2p + (size_t)k * 512);

  // ---- stage 1: one-hot input rows in LDS (bf16), K padded 36->64; 1 row/lane ----
  {
    const float* xr = x + (size_t)(row0 + lr0 + lane) * 15;
    unsigned short* dst = su + lane * 72;
    bf16x8 z = {0, 0, 0, 0, 0, 0, 0, 0};
#pragma unroll
    for (int c = 8; c < 64; c += 8) *(bf16x8*)(dst + c) = z;   // zero cols 8..63
    u32 p[4];
#pragma unroll
    for (int i = 0; i < 4; ++i) p[i] = cvtpk(xr[2 * i], xr[2 * i + 1]);
    *(bf16x8*)dst = *(bf16x8*)p;                 // keep cols 0..7
    *(u32*)(dst + 8) = cvtpk(xr[8], xr[9]);      // keep cols 8..9
    dst[10] = f2bf(xr[10]);                      // keep col 10
    int hold = (int)xr[11]; hold = hold < 0 ? 0 : (hold > 3 ? 3 : hold);
    dst[11 + hold] = 0x3F80;                     // bf16 1.0
#pragma unroll
    for (int t = 0; t < 3; ++t) {
      int nx = (int)xr[12 + t] - 1; nx = nx < 0 ? 0 : (nx > 6 ? 6 : nx);
      dst[15 + t * 7 + nx] = 0x3F80;
    }
  }

  const f32x4 vzero = {0.f, 0.f, 0.f, 0.f};

  // ---- stage 2: h1^T = relu(W1^T @ inp^T + b1), two mt-halves; af1 frags to regs.
  bf16x8 ib[4][2];
#pragma unroll
  for (int rg = 0; rg < 4; ++rg)
#pragma unroll
    for (int ks = 0; ks < 2; ++ks)
      ib[rg][ks] = *(const bf16x8*)(su + (rg * 16 + l16) * 72 + ks * 32 + quad * 8);

  bf16x8 af1[4][4];   // [rg][ks_out]: h1 B-frags, filled per half
#pragma unroll
  for (int half = 0; half < 2; ++half) {
    // hoist this half's 8 W1 frags before the MFMA burst (latency overlap)
    bf16x8 wa[4][2];
#pragma unroll
    for (int mtl = 0; mtl < 4; ++mtl)
#pragma unroll
      for (int ks = 0; ks < 2; ++ks)
        wa[mtl][ks] = *(const bf16x8*)(
            wf + (size_t)(((half * 4 + mtl) * 2 + ks) * 64 + lane) * 8);

    f32x4 acc1[4][4];   // [mtl][rg]
#pragma unroll
    for (int mtl = 0; mtl < 4; ++mtl)
#pragma unroll
      for (int rg = 0; rg < 4; ++rg) acc1[mtl][rg] = vzero;

#pragma unroll
    for (int mtl = 0; mtl < 4; ++mtl)
#pragma unroll
      for (int ks = 0; ks < 2; ++ks)
#pragma unroll
        for (int rg = 0; rg < 4; ++rg)
          acc1[mtl][rg] = __builtin_amdgcn_mfma_f32_16x16x32_bf16(wa[mtl][ks], ib[rg][ks], acc1[mtl][rg], 0, 0, 0);

#pragma unroll
    for (int mtl = 0; mtl < 4; ++mtl) {
      f32x4 bias = *(const f32x4*)(b1 + (half * 4 + mtl) * 16 + quad * 4);
#pragma unroll
      for (int rg = 0; rg < 4; ++rg) {
        float v0 = fmaxf(acc1[mtl][rg][0] + bias[0], 0.f);
        float v1 = fmaxf(acc1[mtl][rg][1] + bias[1], 0.f);
        float v2 = fmaxf(acc1[mtl][rg][2] + bias[2], 0.f);
        float v3 = fmaxf(acc1[mtl][rg][3] + bias[3], 0.f);
        uint2 pk = {cvtpk(v0, v1), cvtpk(v2, v3)};
        *(uint2*)(su + (rg * 16 + l16) * 72 + mtl * 16 + quad * 4) = pk;
      }
    }
#pragma unroll
    for (int rg = 0; rg < 4; ++rg)
#pragma unroll
      for (int ksl = 0; ksl < 2; ++ksl)
        af1[rg][half * 2 + ksl] =
            *(const bf16x8*)(su + (rg * 16 + l16) * 72 + ksl * 32 + quad * 8);
  }

  f32x4 accO[3][4];
#pragma unroll
  for (int mt = 0; mt < 3; ++mt)
#pragma unroll
    for (int rg = 0; rg < 4; ++rg) accO[mt][rg] = vzero;

  // ---- stage 3: register-pipelined W2 K-loop, no barriers ----
  // frag-quad f covers (chunk,mtl) = (f/16, (f%16)/4); 32 quads total.
  for (int chunk = 0; chunk < 8; ++chunk) {
    // W4 frags for this chunk: issued at chunk start, used after 64 MFMAs
    bf16x8 w4r[2][3];
#pragma unroll
    for (int ks3 = 0; ks3 < 2; ++ks3)
#pragma unroll
      for (int mt3 = 0; mt3 < 3; ++mt3)
        w4r[ks3][mt3] = *(const bf16x8*)(
            w4f + (size_t)((mt3 * 16 + chunk * 2 + ks3) * 64 + lane) * 8);

#pragma unroll
    for (int mtl = 0; mtl < 4; ++mtl) {
      // prefetch next frag-quad (one full mtl-step = 16 MFMAs ahead)
      int fb = chunk * 16 + mtl * 4 + 4;
      if (fb >= 128) fb = 0;             // harmless redundant load on last step
      bf16x8 nxtW[4];
#pragma unroll
      for (int k = 0; k < 4; ++k)
        nxtW[k] = *(const bf16x8*)(w2p + (size_t)(fb + k) * 512);

      f32x4 acc2[4];                     // [rg]
#pragma unroll
      for (int rg = 0; rg < 4; ++rg) acc2[rg] = vzero;
#pragma unroll
      for (int ks = 0; ks < 4; ++ks)
#pragma unroll
        for (int rg = 0; rg < 4; ++rg)
          acc2[rg] = __builtin_amdgcn_mfma_f32_16x16x32_bf16(curW[ks], af1[rg][ks], acc2[rg], 0, 0, 0);

      // bias+relu -> h2 cols mtl*16 + quad*4, wave-private b64 writes
      f32x4 bias = *(const f32x4*)(b2 + chunk * 64 + mtl * 16 + quad * 4);
#pragma unroll
      for (int rg = 0; rg < 4; ++rg) {
        float v0 = fmaxf(acc2[rg][0] + bias[0], 0.f);
        float v1 = fmaxf(acc2[rg][1] + bias[1], 0.f);
        float v2 = fmaxf(acc2[rg][2] + bias[2], 0.f);
        float v3 = fmaxf(acc2[rg][3] + bias[3], 0.f);
        uint2 pk = {cvtpk(v0, v1), cvtpk(v2, v3)};
        *(uint2*)(su + (rg * 16 + l16) * 72 + mtl * 16 + quad * 4) = pk;
      }
#pragma unroll
      for (int k = 0; k < 4; ++k) curW[k] = nxtW[k];
    }

    // L3 partial on this chunk's 64 feats (h2 wave-private; W4 from registers)
#pragma unroll
    for (int ks3 = 0; ks3 < 2; ++ks3) {
      bf16x8 h[4];
#pragma unroll
      for (int rg = 0; rg < 4; ++rg)
        h[rg] = *(const bf16x8*)(su + (rg * 16 + l16) * 72 + ks3 * 32 + quad * 8);
#pragma unroll
      for (int mt3 = 0; mt3 < 3; ++mt3)
#pragma unroll
        for (int rg = 0; rg < 4; ++rg)
          accO[mt3][rg] = __builtin_amdgcn_mfma_f32_16x16x32_bf16(w4r[ks3][mt3], h[rg], accO[mt3][rg], 0, 0, 0);
    }
  }

  // ---- epilogue: +b4, float4 stores (lane holds 4 consecutive out-cols) ----
#pragma unroll
  for (int mt3 = 0; mt3 < 3; ++mt3) {
    int colbase = mt3 * 16 + quad * 4;
    if (colbase < 40) {                      // drops pad cols 40..47
      f32x4 bias = *(const f32x4*)(b4 + colbase);
#pragma unroll
      for (int rg = 0; rg < 4; ++rg) {
        f32x4 v = accO[mt3][rg] + bias;
        size_t row = (size_t)(row0 + lr0 + rg * 16 + l16);
        *(f32x4*)(out + row * 40 + colbase) = v;
      }
    }
  }
}

extern "C" void kernel_launch(void* const* d_in, const int* in_sizes, int n_in,
                              void* d_out, int out_size, void* d_ws, size_t ws_size,
                              hipStream_t stream) {
  const float* x  = (const float*)d_in[0];
  const float* W1 = (const float*)d_in[1];
  const float* b1 = (const float*)d_in[2];
  const float* W2 = (const float*)d_in[3];
  const float* b2 = (const float*)d_in[4];
  const float* W4 = (const float*)d_in[5];
  const float* b4 = (const float*)d_in[6];
  float* out = (float*)d_out;
  unsigned short* wf = (unsigned short*)d_ws;   // 192 KB of ws

  int B = in_sizes[0] / 15;

  hipLaunchKernelGGL(pack_weights, dim3((PACK_THREADS + 255) / 256), dim3(256), 0, stream,
                     W1, W2, W4, wf);
  hipLaunchKernelGGL(dqn_fused, dim3(B / 128), dim3(128), 0, stream,
                     x, wf, b1, b2, b4, out);
}